// Round 1
// baseline (453.297 us; speedup 1.0000x reference)
//
#include <hip/hip_runtime.h>

typedef __attribute__((ext_vector_type(8))) short short8;
typedef __attribute__((ext_vector_type(4))) float f32x4;

#define B_    8
#define CI    256
#define CO    256
#define Hh    160
#define Ww    160
#define HP    162
#define WP    162
#define HWp   (Hh * Ww)            // 25600
#define NPIX  (B_ * HWp)           // 204800
#define XPAD_ELEMS (B_ * HP * WP * CI)  // 53,747,712 bf16
#define W2_ELEMS   (9 * CI * CO)        // 589,824 bf16

__device__ __forceinline__ unsigned short f2bf(float f) {
  unsigned int u = __float_as_uint(f);
  u += 0x7FFFu + ((u >> 16) & 1u);   // RNE
  return (unsigned short)(u >> 16);
}

// weight [co][ci][3][3] f32  ->  w2 [s=kh*3+kw][co][ci] bf16 (ci contiguous)
__global__ void prep_w_kernel(const float* __restrict__ w, unsigned short* __restrict__ w2) {
  int i = blockIdx.x * 256 + threadIdx.x;      // i = ((s*256+co)*256+ci)
  if (i >= W2_ELEMS) return;
  int ci = i & 255;
  int t = i >> 8;
  int co = t & 255;
  int s = t >> 8;
  w2[i] = f2bf(w[(co * 256 + ci) * 9 + s]);
}

// ori [n][ci][h][w] f32 * mask [n][1][h][w] -> xp [n][h+1][w+1][ci] bf16 (padded NHWC)
__global__ void prep_x_kernel(const float* __restrict__ ori, const int* __restrict__ mask,
                              unsigned short* __restrict__ xp) {
  int bid = blockIdx.x;                 // (n,h,cit,wt): ((n*160+h)*4+cit)*3+wt
  int wt = bid % 3;
  int t1 = bid / 3;
  int cit = t1 & 3;
  int t2 = t1 >> 2;
  int h = t2 % Hh;
  int n = t2 / Hh;
  int t = threadIdx.x;

  __shared__ float tile[64][65];        // [ci_local][w_local], +1 pad

  int wl = t & 63;
  int w = wt * 64 + wl;
  bool valid = (w < Ww);
  float m = 0.f;
  if (valid) m = (float)mask[(n * Hh + h) * Ww + w];
  const float* src = ori + (((size_t)(n * CI + cit * 64) * Hh + h) * Ww + w);
  int r0 = t >> 6;                      // 0..3
#pragma unroll
  for (int k = 0; k < 16; ++k) {
    int ci_l = r0 * 16 + k;
    float v = 0.f;
    if (valid) v = src[(size_t)ci_l * HWp] * m;
    tile[ci_l][wl] = v;
  }
  __syncthreads();

  int wl2 = t >> 2;                     // 0..63 pixel
  int wo = wt * 64 + wl2;
  if (wo < Ww) {
    int cseg = (t & 3) * 16;
    union { unsigned short u[8]; uint4 v; } p0, p1;
#pragma unroll
    for (int j = 0; j < 8; ++j) p0.u[j] = f2bf(tile[cseg + j][wl2]);
#pragma unroll
    for (int j = 0; j < 8; ++j) p1.u[j] = f2bf(tile[cseg + 8 + j][wl2]);
    unsigned short* dst = xp + ((size_t)((n * HP + h + 1) * WP) + (wo + 1)) * CI + cit * 64 + cseg;
    *(uint4*)dst = p0.v;
    *(uint4*)(dst + 8) = p1.v;
  }
}

__device__ __forceinline__ void gload16(const unsigned short* g, unsigned short* l) {
  __builtin_amdgcn_global_load_lds((const __attribute__((address_space(1))) void*)g,
                                   (__attribute__((address_space(3))) void*)l, 16, 0, 0);
}

// swizzled ds_read_b128: LDS[row][col16 ^ (row&7)] holds global slot col16
__device__ __forceinline__ short8 ldsfrag(const unsigned short* tile, int row, int kk, int lane) {
  int col = ((kk << 2) + (lane >> 4)) ^ (lane & 7);
  return *(const short8*)(tile + row * 64 + col * 8);
}

// Implicit GEMM: Out[co][pix] = sum_{s,ci} W2[s][co][ci] * Xp[pix+shift(s)][ci]
// tile: 128 co x 128 pixels, BK=64, 36 chunks (9 shifts x 4 ci-chunks)
__global__ void __launch_bounds__(256) sconv_gemm(const unsigned short* __restrict__ xp,
                                                  const unsigned short* __restrict__ w2,
                                                  const float* __restrict__ bias,
                                                  float* __restrict__ out) {
  __shared__ unsigned short As[128 * 64];   // [co_local][ci] 16KB
  __shared__ unsigned short Bs[128 * 64];   // [pix_local][ci] 16KB

  int bid = blockIdx.x;
  int cot = bid & 1;
  int pt = bid >> 1;
  int co0 = cot * 128;
  int p0 = pt * 128;
  int t = threadIdx.x;
  int l = t & 63;
  int wv = t >> 6;
  int wrow = wv & 1;      // co half
  int wcol = wv >> 1;     // pixel half

  // staging: lane writes LDS slot (l&7) of row (l>>3); global slot pre-swizzled
  int swz = ((l & 7) ^ (l >> 3)) * 8;
  unsigned int aoff[4], boff[4];
#pragma unroll
  for (int i = 0; i < 4; ++i) {
    int row = wv * 32 + i * 8 + (l >> 3);
    aoff[i] = (unsigned)(co0 + row) * CI + swz;
    int p = p0 + row;
    int n = p / HWp;
    int hw = p - n * HWp;
    int hh = hw / Ww;
    int ww = hw - hh * Ww;
    boff[i] = (unsigned)((n * HP + hh) * WP + ww) * CI + swz;
  }

  f32x4 acc[4][4];
#pragma unroll
  for (int mi = 0; mi < 4; ++mi)
#pragma unroll
    for (int ni = 0; ni < 4; ++ni)
      acc[mi][ni] = (f32x4){0.f, 0.f, 0.f, 0.f};

  for (int ch = 0; ch < 36; ++ch) {
    int shift = ch >> 2;              // 0..8
    int kh = shift / 3;
    int kw = shift - kh * 3;
    int ci0 = (ch & 3) << 6;
    unsigned ad = (unsigned)shift * (CI * CO) + ci0;
    unsigned bd = (unsigned)(kh * WP + kw) * CI + ci0;

    __syncthreads();
#pragma unroll
    for (int i = 0; i < 4; ++i) {
      gload16(w2 + aoff[i] + ad, As + (wv * 4 + i) * 512);
      gload16(xp + boff[i] + bd, Bs + (wv * 4 + i) * 512);
    }
    __syncthreads();

#pragma unroll
    for (int kk = 0; kk < 2; ++kk) {
      short8 a[4], b[4];
#pragma unroll
      for (int mi = 0; mi < 4; ++mi) a[mi] = ldsfrag(As, wrow * 64 + mi * 16 + (l & 15), kk, l);
#pragma unroll
      for (int ni = 0; ni < 4; ++ni) b[ni] = ldsfrag(Bs, wcol * 64 + ni * 16 + (l & 15), kk, l);
#pragma unroll
      for (int mi = 0; mi < 4; ++mi)
#pragma unroll
        for (int ni = 0; ni < 4; ++ni)
          acc[mi][ni] = __builtin_amdgcn_mfma_f32_16x16x32_bf16(a[mi], b[ni], acc[mi][ni], 0, 0, 0);
    }
  }

  // epilogue: D row=co (=(l>>4)*4+r), col=pixel (=l&15)
  int lr4 = (l >> 4) * 4;
  int lc = l & 15;
#pragma unroll
  for (int ni = 0; ni < 4; ++ni) {
    int pixel = p0 + wcol * 64 + ni * 16 + lc;
    int n = pixel / HWp;
    int hw = pixel - n * HWp;
    float* op = out + (size_t)n * (CO * HWp) + hw;
#pragma unroll
    for (int mi = 0; mi < 4; ++mi) {
      int cobase = co0 + wrow * 64 + mi * 16 + lr4;
      const float4 bv = *(const float4*)(bias + cobase);
      f32x4 v = acc[mi][ni];
      op[(size_t)(cobase + 0) * HWp] = v[0] + bv.x;
      op[(size_t)(cobase + 1) * HWp] = v[1] + bv.y;
      op[(size_t)(cobase + 2) * HWp] = v[2] + bv.z;
      op[(size_t)(cobase + 3) * HWp] = v[3] + bv.w;
    }
  }
}

extern "C" void kernel_launch(void* const* d_in, const int* in_sizes, int n_in,
                              void* d_out, int out_size, void* d_ws, size_t ws_size,
                              hipStream_t stream) {
  const int* mask = (const int*)d_in[0];
  const float* ori = (const float*)d_in[1];
  const float* weight = (const float*)d_in[2];
  const float* bias = (const float*)d_in[3];
  float* out = (float*)d_out;

  unsigned short* xp = (unsigned short*)d_ws;          // padded NHWC bf16, 107.5 MB
  unsigned short* w2 = xp + XPAD_ELEMS;                // 1.2 MB

  hipMemsetAsync(xp, 0, (size_t)XPAD_ELEMS * 2, stream);   // zero borders (and interior)
  prep_w_kernel<<<(W2_ELEMS + 255) / 256, 256, 0, stream>>>(weight, w2);
  prep_x_kernel<<<B_ * Hh * 4 * 3, 256, 0, stream>>>(ori, mask, xp);
  sconv_gemm<<<3200, 256, 0, stream>>>(xp, w2, bias, out);
}

// Round 2
// 343.544 us; speedup vs baseline: 1.3195x; 1.3195x over previous
//
#include <hip/hip_runtime.h>

typedef __attribute__((ext_vector_type(8))) short short8;
typedef __attribute__((ext_vector_type(4))) float f32x4;

#define B_    8
#define CI    256
#define CO    256
#define Hh    160
#define Ww    160
#define HP    162
#define WP    162
#define HWp   (Hh * Ww)            // 25600
#define XPAD_ELEMS (B_ * HP * WP * CI)  // 53,747,712 bf16
#define W2_ELEMS   (9 * CI * CO)        // 589,824 bf16
#define NT    36                        // K-tiles: 9 shifts x 4 ci-chunks, BK=64

__device__ __forceinline__ unsigned short f2bf(float f) {
  unsigned int u = __float_as_uint(f);
  u += 0x7FFFu + ((u >> 16) & 1u);   // RNE
  return (unsigned short)(u >> 16);
}

// weight [co][ci][3][3] f32  ->  w2 [s=kh*3+kw][co][ci] bf16 (ci contiguous)
__global__ void prep_w_kernel(const float* __restrict__ w, unsigned short* __restrict__ w2) {
  int i = blockIdx.x * 256 + threadIdx.x;
  if (i >= W2_ELEMS) return;
  int ci = i & 255;
  int t = i >> 8;
  int co = t & 255;
  int s = t >> 8;
  w2[i] = f2bf(w[(co * 256 + ci) * 9 + s]);
}

// zero the padded border of xp (rows 0,161 and cols 0,161 per image)
__global__ void zero_border(unsigned short* __restrict__ xp) {
  int g = blockIdx.x * 256 + threadIdx.x;   // 644 blocks * 256 = 164864 = 5152 pos * 32
  int pos = g >> 5;
  int c = (g & 31) << 3;
  int n = pos / 644;
  int p = pos - n * 644;
  int y, x;
  if (p < 324) { y = (p < 162) ? 0 : 161; x = (p < 162) ? p : p - 162; }
  else { int q = p - 324; y = 1 + (q >> 1); x = (q & 1) ? 161 : 0; }
  unsigned short* d = xp + (((size_t)(n * 162 + y)) * 162 + x) * 256 + c;
  *(uint4*)d = (uint4){0u, 0u, 0u, 0u};
}

// ori [n][ci][h][w] f32 * mask [n][1][h][w] -> xp [n][h+1][w+1][ci] bf16 (padded NHWC)
__global__ void prep_x_kernel(const float* __restrict__ ori, const int* __restrict__ mask,
                              unsigned short* __restrict__ xp) {
  int bid = blockIdx.x;                 // ((n*160+h)*4+cit)*3+wt
  int wt = bid % 3;
  int t1 = bid / 3;
  int cit = t1 & 3;
  int t2 = t1 >> 2;
  int h = t2 % Hh;
  int n = t2 / Hh;
  int t = threadIdx.x;

  __shared__ float tile[64][65];

  int wl = t & 63;
  int w = wt * 64 + wl;
  bool valid = (w < Ww);
  float m = 0.f;
  if (valid) m = (float)mask[(n * Hh + h) * Ww + w];
  const float* src = ori + (((size_t)(n * CI + cit * 64) * Hh + h) * Ww + w);
  int r0 = t >> 6;
#pragma unroll
  for (int k = 0; k < 16; ++k) {
    int ci_l = r0 * 16 + k;
    float v = 0.f;
    if (valid) v = src[(size_t)ci_l * HWp] * m;
    tile[ci_l][wl] = v;
  }
  __syncthreads();

  int wl2 = t >> 2;
  int wo = wt * 64 + wl2;
  if (wo < Ww) {
    int cseg = (t & 3) * 16;
    union { unsigned short u[8]; uint4 v; } p0, p1;
#pragma unroll
    for (int j = 0; j < 8; ++j) p0.u[j] = f2bf(tile[cseg + j][wl2]);
#pragma unroll
    for (int j = 0; j < 8; ++j) p1.u[j] = f2bf(tile[cseg + 8 + j][wl2]);
    unsigned short* dst = xp + ((size_t)((n * HP + h + 1) * WP) + (wo + 1)) * CI + cit * 64 + cseg;
    *(uint4*)dst = p0.v;
    *(uint4*)(dst + 8) = p1.v;
  }
}

__device__ __forceinline__ void gload16(const unsigned short* g, unsigned short* l) {
  __builtin_amdgcn_global_load_lds((const __attribute__((address_space(1))) void*)g,
                                   (__attribute__((address_space(3))) void*)l, 16, 0, 0);
}

// Implicit GEMM, 2-phase counted prefetch.
// Block: 256 co x 160 pixels (one image row), BK=64, 36 K-tiles.
// 512 threads = 8 waves, wave (wm=wv&3, wn=wv>>2) -> 64co x 80pix, acc[4][5].
// LDS: 2 slots, each A[256][64] + B[160][64] bf16 = 52KB; total 104KB. 1 block/CU.
// Swizzle: LDS 16B-slot j of row holds global slot j^(row&7) (both-sides XOR).
__global__ void __launch_bounds__(512, 2) sconv_gemm(const unsigned short* __restrict__ xp,
                                                     const unsigned short* __restrict__ w2,
                                                     const float* __restrict__ bias,
                                                     float* __restrict__ out) {
  __shared__ unsigned short lds[2][26624];   // [slot][A:16384 | B:10240]

  const int bid = blockIdx.x;
  const int n = bid & 7;        // XCD k owns image k (grid 1280 = 8*160)
  const int h = bid >> 3;       // output row

  const int t = threadIdx.x;
  const int l = t & 63;
  const int wv = t >> 6;
  const int wm = wv & 3;        // co quarter
  const int wn = wv >> 2;       // pixel half

  // staging: lane covers row (wv*8 + (l>>3)) within a 64-row round, 16B slot (l&7)
  const int lr = l >> 3;
  const int lane_stage = (wv * 8 + lr) * 256 + (((l & 7) ^ lr) << 3);
  const unsigned xrow_base = (unsigned)(n * HP + h) * WP;   // padded row h+kh at +kh*WP

  // fragment read swizzle: col slot = ((kk<<2)+(l>>4)) ^ (l&7)
  const int lc = l & 15;
  const int cs0 = (((l >> 4)) ^ (l & 7)) << 3;
  const int cs1 = ((4 + (l >> 4)) ^ (l & 7)) << 3;

  f32x4 acc[4][5];
#pragma unroll
  for (int mi = 0; mi < 4; ++mi)
#pragma unroll
    for (int ni = 0; ni < 5; ++ni)
      acc[mi][ni] = (f32x4){0.f, 0.f, 0.f, 0.f};

  auto STAGE = [&](int tt) {
    int shift = tt >> 2;                 // 0..8
    int kh = shift / 3;
    int kw = shift - kh * 3;
    int ci0 = (tt & 3) << 6;
    const unsigned short* ag = w2 + shift * (CI * CO) + ci0 + lane_stage;
    const unsigned short* bg = xp + ((size_t)(xrow_base + kh * WP + kw) << 8) + ci0 + lane_stage;
    unsigned short* sa = &lds[tt & 1][0];
    unsigned short* sb = &lds[tt & 1][16384];
#pragma unroll
    for (int r = 0; r < 4; ++r)
      gload16(ag + r * 16384, sa + (r * 64 + wv * 8) * 64);
#pragma unroll
    for (int r = 0; r < 2; ++r)
      gload16(bg + r * 16384, sb + (r * 64 + wv * 8) * 64);
    if (wv < 4)
      gload16(bg + 32768, sb + (128 + wv * 8) * 64);
  };

  // prologue: fill both slots; wait slot 0 only (stage(1) stays in flight)
  STAGE(0);
  STAGE(1);
  asm volatile("s_waitcnt vmcnt(6)" ::: "memory");
  __builtin_amdgcn_s_barrier();

  for (int tt = 0; tt < NT; ++tt) {
    const unsigned short* Ab = &lds[tt & 1][0];
    const unsigned short* Bb = &lds[tt & 1][16384];

    short8 bf[5][2];
#pragma unroll
    for (int ni = 0; ni < 5; ++ni) {
      const unsigned short* br = Bb + (wn * 80 + ni * 16 + lc) * 64;
      bf[ni][0] = *(const short8*)(br + cs0);
      bf[ni][1] = *(const short8*)(br + cs1);
    }
#pragma unroll
    for (int mi = 0; mi < 4; ++mi) {
      const unsigned short* ar = Ab + (wm * 64 + mi * 16 + lc) * 64;
      short8 a0 = *(const short8*)(ar + cs0);
      short8 a1 = *(const short8*)(ar + cs1);
      __builtin_amdgcn_s_setprio(1);
#pragma unroll
      for (int ni = 0; ni < 5; ++ni) {
        acc[mi][ni] = __builtin_amdgcn_mfma_f32_16x16x32_bf16(a0, bf[ni][0], acc[mi][ni], 0, 0, 0);
        acc[mi][ni] = __builtin_amdgcn_mfma_f32_16x16x32_bf16(a1, bf[ni][1], acc[mi][ni], 0, 0, 0);
      }
      __builtin_amdgcn_s_setprio(0);
    }

    // drains stage(tt+1) (in flight for one full compute phase) + syncs waves;
    // then slot[tt&1] is dead -> refill it for tile tt+2 (flies across next compute)
    __syncthreads();
    if (tt + 2 < NT) STAGE(tt + 2);
  }

  // epilogue: D row=co ((l>>4)*4+j), col=pixel (l&15)
  const int co_l = (l >> 4) * 4;
#pragma unroll
  for (int mi = 0; mi < 4; ++mi) {
    int cobase = wm * 64 + mi * 16 + co_l;
    const float4 bv = *(const float4*)(bias + cobase);
    size_t obase = ((size_t)n * CO + cobase) * HWp + (size_t)h * Ww;
#pragma unroll
    for (int ni = 0; ni < 5; ++ni) {
      int w = wn * 80 + ni * 16 + lc;
      f32x4 v = acc[mi][ni];
      out[obase + w]             = v[0] + bv.x;
      out[obase + HWp + w]       = v[1] + bv.y;
      out[obase + 2 * HWp + w]   = v[2] + bv.z;
      out[obase + 3 * HWp + w]   = v[3] + bv.w;
    }
  }
}

extern "C" void kernel_launch(void* const* d_in, const int* in_sizes, int n_in,
                              void* d_out, int out_size, void* d_ws, size_t ws_size,
                              hipStream_t stream) {
  const int* mask = (const int*)d_in[0];
  const float* ori = (const float*)d_in[1];
  const float* weight = (const float*)d_in[2];
  const float* bias = (const float*)d_in[3];
  float* out = (float*)d_out;

  unsigned short* xp = (unsigned short*)d_ws;          // padded NHWC bf16, 107.5 MB
  unsigned short* w2 = xp + XPAD_ELEMS;                // 1.2 MB

  zero_border<<<644, 256, 0, stream>>>(xp);
  prep_w_kernel<<<(W2_ELEMS + 255) / 256, 256, 0, stream>>>(weight, w2);
  prep_x_kernel<<<B_ * Hh * 4 * 3, 256, 0, stream>>>(ori, mask, xp);
  sconv_gemm<<<B_ * Hh, 512, 0, stream>>>(xp, w2, bias, out);
}